// Round 1
// baseline (20720.901 us; speedup 1.0000x reference)
//
#include <hip/hip_runtime.h>
#include <hip/hip_cooperative_groups.h>
#include <stdint.h>

typedef __attribute__((ext_vector_type(8))) short short8;
typedef __attribute__((ext_vector_type(4))) float floatx4;

#define S_LEN 512
#define BATCH 64
#define HID   1024
#define GATES 4096
#define EMB   1024
#define M_ROWS 32768  // S*B

__device__ __forceinline__ short f2bf(float f) {
  unsigned u = __float_as_uint(f);
  unsigned r = (u + 0x7fffu + ((u >> 16) & 1u)) >> 16;
  return (short)r;
}
__device__ __forceinline__ float bf2f(short v) {
  return __uint_as_float(((unsigned)(unsigned short)v) << 16);
}
__device__ __forceinline__ void ld_lds16(const void* g, void* l) {
  __builtin_amdgcn_global_load_lds((const __attribute__((address_space(1))) void*)g,
                                   (__attribute__((address_space(3))) void*)l, 16, 0, 0);
}

// ---------------- embedding gather: X[s*64+b][k] = bf16(table[tok[b][s]][k])
__global__ __launch_bounds__(256) void k_gather(const int* __restrict__ tok,
                                                const float* __restrict__ table,
                                                short* __restrict__ X) {
  int r = blockIdx.x;
  int b = r & 63, s = r >> 6;
  int t = tok[b * S_LEN + s];
  const float* src = table + (size_t)t * EMB;
  short* dst = X + (size_t)r * EMB;
  for (int k = threadIdx.x; k < EMB; k += 256) dst[k] = f2bf(src[k]);
}

// ---------------- transpose W (1024 x 4096 fp32) -> WT (4096 x 1024 bf16)
__global__ __launch_bounds__(256) void k_transpose(const float* __restrict__ W,
                                                   short* __restrict__ WT) {
  __shared__ short tile[32][33];
  int k0 = blockIdx.x * 32, n0 = blockIdx.y * 32;
  int tx = threadIdx.x & 31, ty = threadIdx.x >> 5;
#pragma unroll
  for (int i = 0; i < 32; i += 8)
    tile[ty + i][tx] = f2bf(W[(size_t)(k0 + ty + i) * GATES + n0 + tx]);
  __syncthreads();
#pragma unroll
  for (int i = 0; i < 32; i += 8)
    WT[(size_t)(n0 + ty + i) * HID + k0 + tx] = tile[tx][ty + i];
}

// ---------------- zero init (h, c state)
__global__ __launch_bounds__(256) void k_zero(uint32_t* p, int n) {
  int i = blockIdx.x * 256 + threadIdx.x;
  if (i < n) p[i] = 0u;
}

// ---------------- input-projection GEMM: Gin = X @ Wx + b   (bf16 out)
// M=32768, N=4096, K=1024. 128x128 tile, BK=32, global_load_lds staging.
__global__ __launch_bounds__(256) void k_gemm_in(const short* __restrict__ X,
                                                 const short* __restrict__ WT_f,
                                                 const short* __restrict__ WT_b,
                                                 const float* __restrict__ bias_f,
                                                 const float* __restrict__ bias_b,
                                                 short* __restrict__ Gin_f,
                                                 short* __restrict__ Gin_b) {
  const short* WT   = blockIdx.z ? WT_b : WT_f;
  const float* bias = blockIdx.z ? bias_b : bias_f;
  short* Gin        = blockIdx.z ? Gin_b : Gin_f;
  __shared__ __align__(16) short sA[128 * 32];
  __shared__ __align__(16) short sB[128 * 32];
  int tid = threadIdx.x;
  int lane = tid & 63, wave = tid >> 6;
  int n0 = blockIdx.x * 128, m0 = blockIdx.y * 128;  // x = N tiles for L2 locality
  int wm = (wave & 1) * 64, wn = (wave >> 1) * 64;
  int lm = lane & 15, lk = (lane >> 4) * 8;
  floatx4 acc[4][4];
  for (int i = 0; i < 4; i++)
    for (int j = 0; j < 4; j++)
      for (int r = 0; r < 4; r++) acc[i][j][r] = 0.f;

  for (int kt = 0; kt < HID; kt += 32) {
    __syncthreads();
#pragma unroll
    for (int i = 0; i < 2; i++) {
      int c = tid + i * 256;
      int row = c >> 2, k8 = (c & 3) * 8;
      ld_lds16(X + (size_t)(m0 + row) * HID + kt + k8, sA + c * 8);
    }
#pragma unroll
    for (int i = 0; i < 2; i++) {
      int c = tid + i * 256;
      int row = c >> 2, k8 = (c & 3) * 8;
      ld_lds16(WT + (size_t)(n0 + row) * HID + kt + k8, sB + c * 8);
    }
    __syncthreads();
    short8 af[4], bf4[4];
#pragma unroll
    for (int mi = 0; mi < 4; mi++) af[mi] = *(const short8*)&sA[(wm + mi * 16 + lm) * 32 + lk];
#pragma unroll
    for (int ni = 0; ni < 4; ni++) bf4[ni] = *(const short8*)&sB[(wn + ni * 16 + lm) * 32 + lk];
#pragma unroll
    for (int mi = 0; mi < 4; mi++)
#pragma unroll
      for (int ni = 0; ni < 4; ni++)
        acc[mi][ni] = __builtin_amdgcn_mfma_f32_16x16x32_bf16(af[mi], bf4[ni], acc[mi][ni], 0, 0, 0);
  }
  int lr = lane >> 4;
#pragma unroll
  for (int mi = 0; mi < 4; mi++)
    for (int ni = 0; ni < 4; ni++)
      for (int r = 0; r < 4; r++) {
        int m = m0 + wm + mi * 16 + lr * 4 + r;
        int n = n0 + wn + ni * 16 + lm;
        Gin[(size_t)m * GATES + n] = f2bf(acc[mi][ni][r] + bias[n]);
      }
}

// ---------------- one LSTM time step, both directions (FALLBACK path only)
__global__ __launch_bounds__(256) void k_step(
    int t, int fused,
    const short* __restrict__ Gin_f, const short* __restrict__ Gin_b,
    const short* __restrict__ X,
    const short* __restrict__ WxT_f, const short* __restrict__ WxT_b,
    const float* __restrict__ bias_f, const float* __restrict__ bias_b,
    const short* __restrict__ WhT_f, const short* __restrict__ WhT_b,
    const short* __restrict__ hin_f, const short* __restrict__ hin_b,
    short* __restrict__ hout_f, short* __restrict__ hout_b,
    float* __restrict__ c_f, float* __restrict__ c_b,
    float* __restrict__ out) {
  int wg = blockIdx.x;
  int dir = wg >> 6;
  int j0 = (wg & 63) * 16;
  int tid = threadIdx.x, lane = tid & 63, g = tid >> 6;
  int lm = lane & 15, lk = (lane >> 4) * 8, lr = lane >> 4;
  int s = dir ? (S_LEN - 1 - t) : t;
  const short* WhT = dir ? WhT_b : WhT_f;
  const short* hin = dir ? hin_b : hin_f;
  short* hout = dir ? hout_b : hout_f;
  float* cbuf = dir ? c_b : c_f;
  int ncol = g * HID + j0 + lm;

  floatx4 acc[4];
  for (int mt = 0; mt < 4; mt++)
    for (int r = 0; r < 4; r++) acc[mt][r] = 0.f;

  {
    const short* Wrow = WhT + (size_t)ncol * HID;
#pragma unroll 4
    for (int kt = 0; kt < HID; kt += 32) {
      short8 bfrag = *(const short8*)&Wrow[kt + lk];
#pragma unroll
      for (int mt = 0; mt < 4; mt++) {
        short8 afrag = *(const short8*)&hin[(mt * 16 + lm) * HID + kt + lk];
        acc[mt] = __builtin_amdgcn_mfma_f32_16x16x32_bf16(afrag, bfrag, acc[mt], 0, 0, 0);
      }
    }
  }
  if (fused) {
    const short* Wrow = (dir ? WxT_b : WxT_f) + (size_t)ncol * HID;
    const short* Xb = X + (size_t)s * BATCH * EMB;
#pragma unroll 4
    for (int kt = 0; kt < EMB; kt += 32) {
      short8 bfrag = *(const short8*)&Wrow[kt + lk];
#pragma unroll
      for (int mt = 0; mt < 4; mt++) {
        short8 afrag = *(const short8*)&Xb[(mt * 16 + lm) * EMB + kt + lk];
        acc[mt] = __builtin_amdgcn_mfma_f32_16x16x32_bf16(afrag, bfrag, acc[mt], 0, 0, 0);
      }
    }
  }

  __shared__ float gl[4][64][16];
  const short* Gin = dir ? Gin_b : Gin_f;
  const float* bias = dir ? bias_b : bias_f;
#pragma unroll
  for (int mt = 0; mt < 4; mt++)
    for (int r = 0; r < 4; r++) {
      int m = mt * 16 + lr * 4 + r;
      float v = acc[mt][r];
      if (fused) v += bias[ncol];
      else       v += bf2f(Gin[(size_t)(s * BATCH + m) * GATES + ncol]);
      gl[g][m][lm] = v;
    }
  __syncthreads();

  for (int p = tid; p < BATCH * 16; p += 256) {
    int m = p >> 4, nl = p & 15;
    int hcol = j0 + nl;
    float iv = gl[0][m][nl], fv = gl[1][m][nl], gv = gl[2][m][nl], ov = gl[3][m][nl];
    float co = cbuf[m * HID + hcol];
    float si = 1.f / (1.f + __expf(-iv));
    float sf = 1.f / (1.f + __expf(-fv));
    float so = 1.f / (1.f + __expf(-ov));
    float cn = sf * co + si * tanhf(gv);
    float hn = so * tanhf(cn);
    cbuf[m * HID + hcol] = cn;
    hout[m * HID + hcol] = f2bf(hn);
    out[(size_t)m * (S_LEN * 2 * HID) + (size_t)s * (2 * HID) + dir * HID + hcol] = hn;
    if (t == S_LEN - 1) {
      size_t hid_base = (size_t)BATCH * S_LEN * 2 * HID;
      out[hid_base + (size_t)m * (2 * HID) + dir * HID + hcol] = hn;
      out[hid_base + (size_t)BATCH * 2 * HID + (size_t)m * (2 * HID) + dir * HID + hcol] = cn;
    }
  }
}

// ---------------- persistent recurrence: all 512 steps in ONE cooperative kernel.
// 256 WGs (1/CU): WG wg -> dir = wg>>7, h-cols j0..j0+7 (32 gate-cols).
// Wh slice lives in REGISTERS for the whole sequence (wr0/wr1: 256 VGPR/lane).
// Wave w owns batch rows w*16..w*16+15 and computes ALL 4 gates for them:
//   acc0 = gates {i (lm<8), f (lm>=8)}, acc1 = gates {g, o}. Pointwise update
//   needs only __shfl_xor(.,8); c state stays in registers across all steps.
__global__ __launch_bounds__(256, 1) void k_recur(
    const short* __restrict__ Gin_f, const short* __restrict__ Gin_b,
    const short* __restrict__ WhT_f, const short* __restrict__ WhT_b,
    short* __restrict__ hf1, short* __restrict__ hf2,
    short* __restrict__ hb1, short* __restrict__ hb2,
    float* __restrict__ out) {
  cooperative_groups::grid_group grid = cooperative_groups::this_grid();
  int wg = blockIdx.x;
  int dir = wg >> 7;
  int j0 = (wg & 127) * 8;
  int tid = threadIdx.x;
  int w = tid >> 6;
  int lane = tid & 63;
  int lm = lane & 15, lr = lane >> 4;
  int lk = lr * 8;
  const short* WhT = dir ? WhT_b : WhT_f;
  const short* Gin = dir ? Gin_b : Gin_f;
  short* hin  = dir ? hb1 : hf1;
  short* hout = dir ? hb2 : hf2;

  // gate-column of this lane's B fragment: acc0 -> gc0 (gates 0/1), acc1 -> gc1 (gates 2/3)
  int gc0 = ((lm >> 3) << 10) + j0 + (lm & 7);
  int gc1 = gc0 + 2048;
  int rowbase = w * 16 + lr * 4;

  // load Wh slice once into registers (static indices -> stays in VGPRs)
  short8 wr0[32], wr1[32];
#pragma unroll
  for (int kt = 0; kt < 32; kt++) {
    wr0[kt] = *(const short8*)&WhT[(size_t)gc0 * HID + kt * 32 + lk];
    wr1[kt] = *(const short8*)&WhT[(size_t)gc1 * HID + kt * 32 + lk];
  }

  float c0 = 0.f, c1 = 0.f;        // persistent cell state (2 rows per lane)
  int rbase = (lm < 8) ? 0 : 2;    // r-split: low lanes rows r=0,1; high lanes r=2,3
  int hcol = j0 + (lm & 7);

  for (int t = 0; t < S_LEN; t++) {
    int s = dir ? (S_LEN - 1 - t) : t;

    // issue Gin loads first: HBM latency hides under the MFMA chain
    const short* gin = Gin + (size_t)s * BATCH * GATES;
    short gv0[4], gv1[4];
#pragma unroll
    for (int r = 0; r < 4; r++) {
      gv0[r] = gin[(size_t)(rowbase + r) * GATES + gc0];
      gv1[r] = gin[(size_t)(rowbase + r) * GATES + gc1];
    }

    floatx4 acc0 = {0.f, 0.f, 0.f, 0.f};
    floatx4 acc1 = {0.f, 0.f, 0.f, 0.f};
    const short* hrow = hin + (size_t)(w * 16 + lm) * HID;
#pragma unroll
    for (int kt = 0; kt < 32; kt++) {
      short8 a = *(const short8*)&hrow[kt * 32 + lk];
      acc0 = __builtin_amdgcn_mfma_f32_16x16x32_bf16(a, wr0[kt], acc0, 0, 0, 0);
      acc1 = __builtin_amdgcn_mfma_f32_16x16x32_bf16(a, wr1[kt], acc1, 0, 0, 0);
    }
#pragma unroll
    for (int r = 0; r < 4; r++) {
      acc0[r] += bf2f(gv0[r]);
      acc1[r] += bf2f(gv1[r]);
    }

    float sw0[4], sw1[4];
#pragma unroll
    for (int r = 0; r < 4; r++) {
      sw0[r] = __shfl_xor(acc0[r], 8, 64);
      sw1[r] = __shfl_xor(acc1[r], 8, 64);
    }

#pragma unroll
    for (int rr = 0; rr < 2; rr++) {
      int r = rbase + rr;
      float iv = (lm < 8) ? acc0[r] : sw0[r];
      float fv = (lm < 8) ? sw0[r] : acc0[r];
      float gg = (lm < 8) ? acc1[r] : sw1[r];
      float ov = (lm < 8) ? sw1[r] : acc1[r];
      float cprev = rr ? c1 : c0;
      float si = 1.f / (1.f + __expf(-iv));
      float sf = 1.f / (1.f + __expf(-fv));
      float so = 1.f / (1.f + __expf(-ov));
      float cn = sf * cprev + si * tanhf(gg);
      float hn = so * tanhf(cn);
      if (rr) c1 = cn; else c0 = cn;
      int row = rowbase + r;
      hout[row * HID + hcol] = f2bf(hn);
      out[(size_t)row * (S_LEN * 2 * HID) + (size_t)s * (2 * HID) + dir * HID + hcol] = hn;
      if (t == S_LEN - 1) {
        size_t hid_base = (size_t)BATCH * S_LEN * 2 * HID;
        out[hid_base + (size_t)row * (2 * HID) + dir * HID + hcol] = hn;
        out[hid_base + (size_t)BATCH * 2 * HID + (size_t)row * (2 * HID) + dir * HID + hcol] = cn;
      }
    }

    grid.sync();  // h(t) visible device-wide; next step reads the other buffer
    short* tmp = hin; hin = hout; hout = tmp;
  }
}

extern "C" void kernel_launch(void* const* d_in, const int* in_sizes, int n_in,
                              void* d_out, int out_size, void* d_ws, size_t ws_size,
                              hipStream_t stream) {
  const int*   tok   = (const int*)d_in[0];
  const float* table = (const float*)d_in[1];
  const float* Wx_f  = (const float*)d_in[2];
  const float* Wh_f  = (const float*)d_in[3];
  const float* b_f   = (const float*)d_in[4];
  const float* Wx_b  = (const float*)d_in[5];
  const float* Wh_b  = (const float*)d_in[6];
  const float* b_b   = (const float*)d_in[7];
  float* out = (float*)d_out;

  char* w = (char*)d_ws;
  short* WxTf = (short*)(w + 0);          // 8 MB each
  short* WxTb = (short*)(w + 8388608);
  short* WhTf = (short*)(w + 16777216);
  short* WhTb = (short*)(w + 25165824);
  char* state = w + 33554432;             // 1 MB state block
  short* h_f1 = (short*)(state);
  short* h_b1 = (short*)(state + 131072);
  float* c_f  = (float*)(state + 262144);
  float* c_b  = (float*)(state + 524288);
  short* h_f2 = (short*)(state + 786432);
  short* h_b2 = (short*)(state + 917504);
  short* X    = (short*)(w + 34603008);   // 64 MB
  short* Ginf = (short*)(w + 101711872);  // 256 MB
  short* Ginb = (short*)(w + 370147328);  // 256 MB
  int fused = (ws_size < 638582784ull) ? 1 : 0;

  k_gather<<<dim3(M_ROWS), dim3(256), 0, stream>>>(tok, table, X);
  k_transpose<<<dim3(32, 128), dim3(256), 0, stream>>>(Wx_f, WxTf);
  k_transpose<<<dim3(32, 128), dim3(256), 0, stream>>>(Wx_b, WxTb);
  k_transpose<<<dim3(32, 128), dim3(256), 0, stream>>>(Wh_f, WhTf);
  k_transpose<<<dim3(32, 128), dim3(256), 0, stream>>>(Wh_b, WhTb);
  k_zero<<<dim3(768), dim3(256), 0, stream>>>((uint32_t*)state, 786432 / 4);

  int use_persistent = 0;
  if (!fused) {
    k_gemm_in<<<dim3(32, 256, 2), dim3(256), 0, stream>>>(X, WxTf, WxTb, b_f, b_b, Ginf, Ginb);
    void* args[9];
    args[0] = (void*)&Ginf;  args[1] = (void*)&Ginb;
    args[2] = (void*)&WhTf;  args[3] = (void*)&WhTb;
    args[4] = (void*)&h_f1;  args[5] = (void*)&h_f2;
    args[6] = (void*)&h_b1;  args[7] = (void*)&h_b2;
    args[8] = (void*)&out;
    hipError_t err = hipLaunchCooperativeKernel((const void*)k_recur, dim3(256), dim3(256),
                                                args, 0, stream);
    if (err == hipSuccess) use_persistent = 1;
    else (void)hipGetLastError();  // clear sticky error, fall back to per-step loop
  }

  if (!use_persistent) {
    for (int t = 0; t < S_LEN; t++) {
      const short* hinf = (t & 1) ? h_f2 : h_f1;
      const short* hinb = (t & 1) ? h_b2 : h_b1;
      short* houtf = (t & 1) ? h_f1 : h_f2;
      short* houtb = (t & 1) ? h_b1 : h_b2;
      k_step<<<dim3(128), dim3(256), 0, stream>>>(t, fused, Ginf, Ginb, X, WxTf, WxTb, b_f, b_b,
                                                  WhTf, WhTb, hinf, hinb, houtf, houtb, c_f, c_b, out);
    }
  }
}

// Round 2
// 18370.459 us; speedup vs baseline: 1.1279x; 1.1279x over previous
//
#include <hip/hip_runtime.h>
#include <stdint.h>

typedef __attribute__((ext_vector_type(8))) short short8;
typedef __attribute__((ext_vector_type(4))) float floatx4;

#define S_LEN 512
#define BATCH 64
#define HID   1024
#define GATES 4096
#define EMB   1024
#define M_ROWS 32768  // S*B

__device__ __forceinline__ short f2bf(float f) {
  unsigned u = __float_as_uint(f);
  unsigned r = (u + 0x7fffu + ((u >> 16) & 1u)) >> 16;
  return (short)r;
}
__device__ __forceinline__ float bf2f(short v) {
  return __uint_as_float(((unsigned)(unsigned short)v) << 16);
}
__device__ __forceinline__ void ld_lds16(const void* g, void* l) {
  __builtin_amdgcn_global_load_lds((const __attribute__((address_space(1))) void*)g,
                                   (__attribute__((address_space(3))) void*)l, 16, 0, 0);
}

// ---------------- embedding gather: X[s*64+b][k] = bf16(table[tok[b][s]][k])
__global__ __launch_bounds__(256) void k_gather(const int* __restrict__ tok,
                                                const float* __restrict__ table,
                                                short* __restrict__ X) {
  int r = blockIdx.x;
  int b = r & 63, s = r >> 6;
  int t = tok[b * S_LEN + s];
  const float* src = table + (size_t)t * EMB;
  short* dst = X + (size_t)r * EMB;
  for (int k = threadIdx.x; k < EMB; k += 256) dst[k] = f2bf(src[k]);
}

// ---------------- transpose W (1024 x 4096 fp32) -> WT (4096 x 1024 bf16)
__global__ __launch_bounds__(256) void k_transpose(const float* __restrict__ W,
                                                   short* __restrict__ WT) {
  __shared__ short tile[32][33];
  int k0 = blockIdx.x * 32, n0 = blockIdx.y * 32;
  int tx = threadIdx.x & 31, ty = threadIdx.x >> 5;
#pragma unroll
  for (int i = 0; i < 32; i += 8)
    tile[ty + i][tx] = f2bf(W[(size_t)(k0 + ty + i) * GATES + n0 + tx]);
  __syncthreads();
#pragma unroll
  for (int i = 0; i < 32; i += 8)
    WT[(size_t)(n0 + ty + i) * HID + k0 + tx] = tile[tx][ty + i];
}

// ---------------- zero init (h, c state, barrier counters)
__global__ __launch_bounds__(256) void k_zero(uint32_t* p, int n) {
  int i = blockIdx.x * 256 + threadIdx.x;
  if (i < n) p[i] = 0u;
}

// ---------------- input-projection GEMM: Gin = X @ Wx + b   (bf16 out)
// M=32768, N=4096, K=1024. 128x128 tile, BK=32, global_load_lds staging.
__global__ __launch_bounds__(256) void k_gemm_in(const short* __restrict__ X,
                                                 const short* __restrict__ WT_f,
                                                 const short* __restrict__ WT_b,
                                                 const float* __restrict__ bias_f,
                                                 const float* __restrict__ bias_b,
                                                 short* __restrict__ Gin_f,
                                                 short* __restrict__ Gin_b) {
  const short* WT   = blockIdx.z ? WT_b : WT_f;
  const float* bias = blockIdx.z ? bias_b : bias_f;
  short* Gin        = blockIdx.z ? Gin_b : Gin_f;
  __shared__ __align__(16) short sA[128 * 32];
  __shared__ __align__(16) short sB[128 * 32];
  int tid = threadIdx.x;
  int lane = tid & 63, wave = tid >> 6;
  int n0 = blockIdx.x * 128, m0 = blockIdx.y * 128;  // x = N tiles for L2 locality
  int wm = (wave & 1) * 64, wn = (wave >> 1) * 64;
  int lm = lane & 15, lk = (lane >> 4) * 8;
  floatx4 acc[4][4];
  for (int i = 0; i < 4; i++)
    for (int j = 0; j < 4; j++)
      for (int r = 0; r < 4; r++) acc[i][j][r] = 0.f;

  for (int kt = 0; kt < HID; kt += 32) {
    __syncthreads();
#pragma unroll
    for (int i = 0; i < 2; i++) {
      int c = tid + i * 256;
      int row = c >> 2, k8 = (c & 3) * 8;
      ld_lds16(X + (size_t)(m0 + row) * HID + kt + k8, sA + c * 8);
    }
#pragma unroll
    for (int i = 0; i < 2; i++) {
      int c = tid + i * 256;
      int row = c >> 2, k8 = (c & 3) * 8;
      ld_lds16(WT + (size_t)(n0 + row) * HID + kt + k8, sB + c * 8);
    }
    __syncthreads();
    short8 af[4], bf4[4];
#pragma unroll
    for (int mi = 0; mi < 4; mi++) af[mi] = *(const short8*)&sA[(wm + mi * 16 + lm) * 32 + lk];
#pragma unroll
    for (int ni = 0; ni < 4; ni++) bf4[ni] = *(const short8*)&sB[(wn + ni * 16 + lm) * 32 + lk];
#pragma unroll
    for (int mi = 0; mi < 4; mi++)
#pragma unroll
      for (int ni = 0; ni < 4; ni++)
        acc[mi][ni] = __builtin_amdgcn_mfma_f32_16x16x32_bf16(af[mi], bf4[ni], acc[mi][ni], 0, 0, 0);
  }
  int lr = lane >> 4;
#pragma unroll
  for (int mi = 0; mi < 4; mi++)
    for (int ni = 0; ni < 4; ni++)
      for (int r = 0; r < 4; r++) {
        int m = m0 + wm + mi * 16 + lr * 4 + r;
        int n = n0 + wn + ni * 16 + lm;
        Gin[(size_t)m * GATES + n] = f2bf(acc[mi][ni][r] + bias[n]);
      }
}

// ---------------- one LSTM time step, both directions (FALLBACK path only)
__global__ __launch_bounds__(256) void k_step(
    int t, int fused,
    const short* __restrict__ Gin_f, const short* __restrict__ Gin_b,
    const short* __restrict__ X,
    const short* __restrict__ WxT_f, const short* __restrict__ WxT_b,
    const float* __restrict__ bias_f, const float* __restrict__ bias_b,
    const short* __restrict__ WhT_f, const short* __restrict__ WhT_b,
    const short* __restrict__ hin_f, const short* __restrict__ hin_b,
    short* __restrict__ hout_f, short* __restrict__ hout_b,
    float* __restrict__ c_f, float* __restrict__ c_b,
    float* __restrict__ out) {
  int wg = blockIdx.x;
  int dir = wg >> 6;
  int j0 = (wg & 63) * 16;
  int tid = threadIdx.x, lane = tid & 63, g = tid >> 6;
  int lm = lane & 15, lk = (lane >> 4) * 8, lr = lane >> 4;
  int s = dir ? (S_LEN - 1 - t) : t;
  const short* WhT = dir ? WhT_b : WhT_f;
  const short* hin = dir ? hin_b : hin_f;
  short* hout = dir ? hout_b : hout_f;
  float* cbuf = dir ? c_b : c_f;
  int ncol = g * HID + j0 + lm;

  floatx4 acc[4];
  for (int mt = 0; mt < 4; mt++)
    for (int r = 0; r < 4; r++) acc[mt][r] = 0.f;

  {
    const short* Wrow = WhT + (size_t)ncol * HID;
#pragma unroll 4
    for (int kt = 0; kt < HID; kt += 32) {
      short8 bfrag = *(const short8*)&Wrow[kt + lk];
#pragma unroll
      for (int mt = 0; mt < 4; mt++) {
        short8 afrag = *(const short8*)&hin[(mt * 16 + lm) * HID + kt + lk];
        acc[mt] = __builtin_amdgcn_mfma_f32_16x16x32_bf16(afrag, bfrag, acc[mt], 0, 0, 0);
      }
    }
  }
  if (fused) {
    const short* Wrow = (dir ? WxT_b : WxT_f) + (size_t)ncol * HID;
    const short* Xb = X + (size_t)s * BATCH * EMB;
#pragma unroll 4
    for (int kt = 0; kt < EMB; kt += 32) {
      short8 bfrag = *(const short8*)&Wrow[kt + lk];
#pragma unroll
      for (int mt = 0; mt < 4; mt++) {
        short8 afrag = *(const short8*)&Xb[(mt * 16 + lm) * EMB + kt + lk];
        acc[mt] = __builtin_amdgcn_mfma_f32_16x16x32_bf16(afrag, bfrag, acc[mt], 0, 0, 0);
      }
    }
  }

  __shared__ float gl[4][64][16];
  const short* Gin = dir ? Gin_b : Gin_f;
  const float* bias = dir ? bias_b : bias_f;
#pragma unroll
  for (int mt = 0; mt < 4; mt++)
    for (int r = 0; r < 4; r++) {
      int m = mt * 16 + lr * 4 + r;
      float v = acc[mt][r];
      if (fused) v += bias[ncol];
      else       v += bf2f(Gin[(size_t)(s * BATCH + m) * GATES + ncol]);
      gl[g][m][lm] = v;
    }
  __syncthreads();

  for (int p = tid; p < BATCH * 16; p += 256) {
    int m = p >> 4, nl = p & 15;
    int hcol = j0 + nl;
    float iv = gl[0][m][nl], fv = gl[1][m][nl], gv = gl[2][m][nl], ov = gl[3][m][nl];
    float co = cbuf[m * HID + hcol];
    float si = 1.f / (1.f + __expf(-iv));
    float sf = 1.f / (1.f + __expf(-fv));
    float so = 1.f / (1.f + __expf(-ov));
    float cn = sf * co + si * tanhf(gv);
    float hn = so * tanhf(cn);
    cbuf[m * HID + hcol] = cn;
    hout[m * HID + hcol] = f2bf(hn);
    out[(size_t)m * (S_LEN * 2 * HID) + (size_t)s * (2 * HID) + dir * HID + hcol] = hn;
    if (t == S_LEN - 1) {
      size_t hid_base = (size_t)BATCH * S_LEN * 2 * HID;
      out[hid_base + (size_t)m * (2 * HID) + dir * HID + hcol] = hn;
      out[hid_base + (size_t)BATCH * 2 * HID + (size_t)m * (2 * HID) + dir * HID + hcol] = cn;
    }
  }
}

// ---------------- persistent recurrence: all 512 steps in ONE cooperative kernel.
// 256 WGs (1/CU): WG wg -> dir = wg>>7, h-cols j0..j0+7 (32 gate-cols).
// Sync: custom two-level agent-scope barrier PER DIRECTION (replaces grid.sync,
// whose single system-scope counter serializes 256 RMWs ~= 36us/step measured).
// Level 1: 8 groups x 16 WGs; level 2: root (8 arrivals); release = epoch t+1.
__global__ __launch_bounds__(256, 1) void k_recur(
    const short* __restrict__ Gin_f, const short* __restrict__ Gin_b,
    const short* __restrict__ WhT_f, const short* __restrict__ WhT_b,
    short* __restrict__ hf1, short* __restrict__ hf2,
    short* __restrict__ hb1, short* __restrict__ hb2,
    unsigned* __restrict__ bar,
    float* __restrict__ out) {
  int wg = blockIdx.x;
  int dir = wg >> 7;
  int l = wg & 127;
  int grp = l >> 4;  // 8 groups of 16 per direction
  int j0 = l * 8;
  int tid = threadIdx.x;
  int w = tid >> 6;
  int lane = tid & 63;
  int lm = lane & 15, lr = lane >> 4;
  int lk = lr * 8;
  const short* WhT = dir ? WhT_b : WhT_f;
  const short* Gin = dir ? Gin_b : Gin_f;
  short* hin  = dir ? hb1 : hf1;
  short* hout = dir ? hb2 : hf2;

  unsigned* l1c = bar + (dir * 8 + grp) * 32;  // 128B-spaced counters
  unsigned* rtc = bar + (16 + dir) * 32;
  unsigned* rel = bar + (18 + dir) * 32;

  // gate-column of this lane's B fragment: acc0 -> gc0 (gates 0/1), acc1 -> gc1 (gates 2/3)
  int gc0 = ((lm >> 3) << 10) + j0 + (lm & 7);
  int gc1 = gc0 + 2048;
  int rowbase = w * 16 + lr * 4;

  // Wh slice into registers (256 VGPR/lane); reused across all 512 steps
  short8 wr0[32], wr1[32];
#pragma unroll
  for (int kt = 0; kt < 32; kt++) {
    wr0[kt] = *(const short8*)&WhT[(size_t)gc0 * HID + kt * 32 + lk];
    wr1[kt] = *(const short8*)&WhT[(size_t)gc1 * HID + kt * 32 + lk];
  }

  float c0 = 0.f, c1 = 0.f;        // persistent cell state (2 rows per lane)
  int rbase = (lm < 8) ? 0 : 2;    // r-split: low lanes rows r=0,1; high lanes r=2,3
  int hcol = j0 + (lm & 7);

  // prefetch Gin for step 0
  short gv0[4], gv1[4];
  {
    int s0 = dir ? (S_LEN - 1) : 0;
    const short* gin = Gin + (size_t)s0 * BATCH * GATES;
#pragma unroll
    for (int r = 0; r < 4; r++) {
      gv0[r] = gin[(size_t)(rowbase + r) * GATES + gc0];
      gv1[r] = gin[(size_t)(rowbase + r) * GATES + gc1];
    }
  }

  for (int t = 0; t < S_LEN; t++) {
    int s = dir ? (S_LEN - 1 - t) : t;

    floatx4 acc0 = {0.f, 0.f, 0.f, 0.f};
    floatx4 acc1 = {0.f, 0.f, 0.f, 0.f};
    const short* hrow = hin + (size_t)(w * 16 + lm) * HID;
#pragma unroll
    for (int kt = 0; kt < 32; kt++) {
      short8 a = *(const short8*)&hrow[kt * 32 + lk];
      acc0 = __builtin_amdgcn_mfma_f32_16x16x32_bf16(a, wr0[kt], acc0, 0, 0, 0);
      acc1 = __builtin_amdgcn_mfma_f32_16x16x32_bf16(a, wr1[kt], acc1, 0, 0, 0);
    }
#pragma unroll
    for (int r = 0; r < 4; r++) {
      acc0[r] += bf2f(gv0[r]);
      acc1[r] += bf2f(gv1[r]);
    }

    float sw0[4], sw1[4];
#pragma unroll
    for (int r = 0; r < 4; r++) {
      sw0[r] = __shfl_xor(acc0[r], 8, 64);
      sw1[r] = __shfl_xor(acc1[r], 8, 64);
    }

#pragma unroll
    for (int rr = 0; rr < 2; rr++) {
      int r = rbase + rr;
      float iv = (lm < 8) ? acc0[r] : sw0[r];
      float fv = (lm < 8) ? sw0[r] : acc0[r];
      float gg = (lm < 8) ? acc1[r] : sw1[r];
      float ov = (lm < 8) ? sw1[r] : acc1[r];
      float cprev = rr ? c1 : c0;
      float si = 1.f / (1.f + __expf(-iv));
      float sf = 1.f / (1.f + __expf(-fv));
      float so = 1.f / (1.f + __expf(-ov));
      float cn = sf * cprev + si * tanhf(gg);
      float hn = so * tanhf(cn);
      if (rr) c1 = cn; else c0 = cn;
      int row = rowbase + r;
      hout[row * HID + hcol] = f2bf(hn);
      out[(size_t)row * (S_LEN * 2 * HID) + (size_t)s * (2 * HID) + dir * HID + hcol] = hn;
      if (t == S_LEN - 1) {
        size_t hid_base = (size_t)BATCH * S_LEN * 2 * HID;
        out[hid_base + (size_t)row * (2 * HID) + dir * HID + hcol] = hn;
        out[hid_base + (size_t)BATCH * 2 * HID + (size_t)row * (2 * HID) + dir * HID + hcol] = cn;
      }
    }

    if (t + 1 < S_LEN) {
      // prefetch next step's Gin BEFORE the barrier: HBM latency hides under sync
      int sn = dir ? (S_LEN - 2 - t) : (t + 1);
      const short* gin = Gin + (size_t)sn * BATCH * GATES;
#pragma unroll
      for (int r = 0; r < 4; r++) {
        gv0[r] = gin[(size_t)(rowbase + r) * GATES + gc0];
        gv1[r] = gin[(size_t)(rowbase + r) * GATES + gc1];
      }

      __syncthreads();  // all WG stores drained (vmcnt 0)
      if (tid == 0) {
        __threadfence();  // agent-scope release: WG's h stores device-visible
        unsigned prev = __hip_atomic_fetch_add(l1c, 1u, __ATOMIC_ACQ_REL, __HIP_MEMORY_SCOPE_AGENT);
        if ((prev & 15u) == 15u) {  // last of 16 in group for this epoch
          unsigned p2 = __hip_atomic_fetch_add(rtc, 1u, __ATOMIC_ACQ_REL, __HIP_MEMORY_SCOPE_AGENT);
          if ((p2 & 7u) == 7u)      // last of 8 groups
            __hip_atomic_store(rel, (unsigned)(t + 1), __ATOMIC_RELEASE, __HIP_MEMORY_SCOPE_AGENT);
        }
        while (__hip_atomic_load(rel, __ATOMIC_ACQUIRE, __HIP_MEMORY_SCOPE_AGENT) < (unsigned)(t + 1)) {
          __builtin_amdgcn_s_sleep(1);
        }
      }
      __syncthreads();
    }
    short* tmp = hin; hin = hout; hout = tmp;
  }
}

extern "C" void kernel_launch(void* const* d_in, const int* in_sizes, int n_in,
                              void* d_out, int out_size, void* d_ws, size_t ws_size,
                              hipStream_t stream) {
  const int*   tok   = (const int*)d_in[0];
  const float* table = (const float*)d_in[1];
  const float* Wx_f  = (const float*)d_in[2];
  const float* Wh_f  = (const float*)d_in[3];
  const float* b_f   = (const float*)d_in[4];
  const float* Wx_b  = (const float*)d_in[5];
  const float* Wh_b  = (const float*)d_in[6];
  const float* b_b   = (const float*)d_in[7];
  float* out = (float*)d_out;

  char* w = (char*)d_ws;
  short* WxTf = (short*)(w + 0);          // 8 MB each
  short* WxTb = (short*)(w + 8388608);
  short* WhTf = (short*)(w + 16777216);
  short* WhTb = (short*)(w + 25165824);
  char* state = w + 33554432;             // 1 MB state block
  short* h_f1 = (short*)(state);
  short* h_b1 = (short*)(state + 131072);
  float* c_f  = (float*)(state + 262144);   // fallback-only; doubles as barrier area
  float* c_b  = (float*)(state + 524288);
  short* h_f2 = (short*)(state + 786432);
  short* h_b2 = (short*)(state + 917504);
  unsigned* bar = (unsigned*)(state + 262144);  // reuses c_f area (zeroed by k_zero)
  short* X    = (short*)(w + 34603008);   // 64 MB
  short* Ginf = (short*)(w + 101711872);  // 256 MB
  short* Ginb = (short*)(w + 370147328);  // 256 MB
  int fused = (ws_size < 638582784ull) ? 1 : 0;

  k_gather<<<dim3(M_ROWS), dim3(256), 0, stream>>>(tok, table, X);
  k_transpose<<<dim3(32, 128), dim3(256), 0, stream>>>(Wx_f, WxTf);
  k_transpose<<<dim3(32, 128), dim3(256), 0, stream>>>(Wx_b, WxTb);
  k_transpose<<<dim3(32, 128), dim3(256), 0, stream>>>(Wh_f, WhTf);
  k_transpose<<<dim3(32, 128), dim3(256), 0, stream>>>(Wh_b, WhTb);
  k_zero<<<dim3(768), dim3(256), 0, stream>>>((uint32_t*)state, 786432 / 4);

  int use_persistent = 0;
  if (!fused) {
    k_gemm_in<<<dim3(32, 256, 2), dim3(256), 0, stream>>>(X, WxTf, WxTb, b_f, b_b, Ginf, Ginb);
    void* args[10];
    args[0] = (void*)&Ginf;  args[1] = (void*)&Ginb;
    args[2] = (void*)&WhTf;  args[3] = (void*)&WhTb;
    args[4] = (void*)&h_f1;  args[5] = (void*)&h_f2;
    args[6] = (void*)&h_b1;  args[7] = (void*)&h_b2;
    args[8] = (void*)&bar;   args[9] = (void*)&out;
    hipError_t err = hipLaunchCooperativeKernel((const void*)k_recur, dim3(256), dim3(256),
                                                args, 0, stream);
    if (err == hipSuccess) use_persistent = 1;
    else (void)hipGetLastError();  // clear sticky error, fall back to per-step loop
  }

  if (!use_persistent) {
    for (int t = 0; t < S_LEN; t++) {
      const short* hinf = (t & 1) ? h_f2 : h_f1;
      const short* hinb = (t & 1) ? h_b2 : h_b1;
      short* houtf = (t & 1) ? h_f1 : h_f2;
      short* houtb = (t & 1) ? h_b1 : h_b2;
      k_step<<<dim3(128), dim3(256), 0, stream>>>(t, fused, Ginf, Ginb, X, WxTf, WxTb, b_f, b_b,
                                                  WhTf, WhTb, hinf, hinb, houtf, houtb, c_f, c_b, out);
    }
  }
}

// Round 4
// 16275.764 us; speedup vs baseline: 1.2731x; 1.1287x over previous
//
#include <hip/hip_runtime.h>
#include <stdint.h>

typedef __attribute__((ext_vector_type(8))) short short8;
typedef __attribute__((ext_vector_type(4))) float floatx4;

#define S_LEN 512
#define BATCH 64
#define HID   1024
#define GATES 4096
#define EMB   1024
#define M_ROWS 32768  // S*B

__device__ __forceinline__ short f2bf(float f) {
  unsigned u = __float_as_uint(f);
  unsigned r = (u + 0x7fffu + ((u >> 16) & 1u)) >> 16;
  return (short)r;
}
__device__ __forceinline__ float bf2f(short v) {
  return __uint_as_float(((unsigned)(unsigned short)v) << 16);
}
__device__ __forceinline__ void ld_lds16(const void* g, void* l) {
  __builtin_amdgcn_global_load_lds((const __attribute__((address_space(1))) void*)g,
                                   (__attribute__((address_space(3))) void*)l, 16, 0, 0);
}

// ---------------- embedding gather: X[s*64+b][k] = bf16(table[tok[b][s]][k])
__global__ __launch_bounds__(256) void k_gather(const int* __restrict__ tok,
                                                const float* __restrict__ table,
                                                short* __restrict__ X) {
  int r = blockIdx.x;
  int b = r & 63, s = r >> 6;
  int t = tok[b * S_LEN + s];
  const float* src = table + (size_t)t * EMB;
  short* dst = X + (size_t)r * EMB;
  for (int k = threadIdx.x; k < EMB; k += 256) dst[k] = f2bf(src[k]);
}

// ---------------- transpose W (1024 x 4096 fp32) -> WT (4096 x 1024 bf16)
__global__ __launch_bounds__(256) void k_transpose(const float* __restrict__ W,
                                                   short* __restrict__ WT) {
  __shared__ short tile[32][33];
  int k0 = blockIdx.x * 32, n0 = blockIdx.y * 32;
  int tx = threadIdx.x & 31, ty = threadIdx.x >> 5;
#pragma unroll
  for (int i = 0; i < 32; i += 8)
    tile[ty + i][tx] = f2bf(W[(size_t)(k0 + ty + i) * GATES + n0 + tx]);
  __syncthreads();
#pragma unroll
  for (int i = 0; i < 32; i += 8)
    WT[(size_t)(n0 + ty + i) * HID + k0 + tx] = tile[tx][ty + i];
}

// ---------------- zero init (h, c state, barrier counters)
__global__ __launch_bounds__(256) void k_zero(uint32_t* p, int n) {
  int i = blockIdx.x * 256 + threadIdx.x;
  if (i < n) p[i] = 0u;
}

// ---------------- input-projection GEMM: Gin = X @ Wx + b   (bf16 out)
__global__ __launch_bounds__(256) void k_gemm_in(const short* __restrict__ X,
                                                 const short* __restrict__ WT_f,
                                                 const short* __restrict__ WT_b,
                                                 const float* __restrict__ bias_f,
                                                 const float* __restrict__ bias_b,
                                                 short* __restrict__ Gin_f,
                                                 short* __restrict__ Gin_b) {
  const short* WT   = blockIdx.z ? WT_b : WT_f;
  const float* bias = blockIdx.z ? bias_b : bias_f;
  short* Gin        = blockIdx.z ? Gin_b : Gin_f;
  __shared__ __align__(16) short sA[128 * 32];
  __shared__ __align__(16) short sB[128 * 32];
  int tid = threadIdx.x;
  int lane = tid & 63, wave = tid >> 6;
  int n0 = blockIdx.x * 128, m0 = blockIdx.y * 128;  // x = N tiles for L2 locality
  int wm = (wave & 1) * 64, wn = (wave >> 1) * 64;
  int lm = lane & 15, lk = (lane >> 4) * 8;
  floatx4 acc[4][4];
  for (int i = 0; i < 4; i++)
    for (int j = 0; j < 4; j++)
      for (int r = 0; r < 4; r++) acc[i][j][r] = 0.f;

  for (int kt = 0; kt < HID; kt += 32) {
    __syncthreads();
#pragma unroll
    for (int i = 0; i < 2; i++) {
      int c = tid + i * 256;
      int row = c >> 2, k8 = (c & 3) * 8;
      ld_lds16(X + (size_t)(m0 + row) * HID + kt + k8, sA + c * 8);
    }
#pragma unroll
    for (int i = 0; i < 2; i++) {
      int c = tid + i * 256;
      int row = c >> 2, k8 = (c & 3) * 8;
      ld_lds16(WT + (size_t)(n0 + row) * HID + kt + k8, sB + c * 8);
    }
    __syncthreads();
    short8 af[4], bf4[4];
#pragma unroll
    for (int mi = 0; mi < 4; mi++) af[mi] = *(const short8*)&sA[(wm + mi * 16 + lm) * 32 + lk];
#pragma unroll
    for (int ni = 0; ni < 4; ni++) bf4[ni] = *(const short8*)&sB[(wn + ni * 16 + lm) * 32 + lk];
#pragma unroll
    for (int mi = 0; mi < 4; mi++)
#pragma unroll
      for (int ni = 0; ni < 4; ni++)
        acc[mi][ni] = __builtin_amdgcn_mfma_f32_16x16x32_bf16(af[mi], bf4[ni], acc[mi][ni], 0, 0, 0);
  }
  int lr = lane >> 4;
#pragma unroll
  for (int mi = 0; mi < 4; mi++)
    for (int ni = 0; ni < 4; ni++)
      for (int r = 0; r < 4; r++) {
        int m = m0 + wm + mi * 16 + lr * 4 + r;
        int n = n0 + wn + ni * 16 + lm;
        Gin[(size_t)m * GATES + n] = f2bf(acc[mi][ni][r] + bias[n]);
      }
}

// ---------------- one LSTM time step, both directions (FALLBACK path only)
__global__ __launch_bounds__(256) void k_step(
    int t, int fused,
    const short* __restrict__ Gin_f, const short* __restrict__ Gin_b,
    const short* __restrict__ X,
    const short* __restrict__ WxT_f, const short* __restrict__ WxT_b,
    const float* __restrict__ bias_f, const float* __restrict__ bias_b,
    const short* __restrict__ WhT_f, const short* __restrict__ WhT_b,
    const short* __restrict__ hin_f, const short* __restrict__ hin_b,
    short* __restrict__ hout_f, short* __restrict__ hout_b,
    float* __restrict__ c_f, float* __restrict__ c_b,
    float* __restrict__ out) {
  int wg = blockIdx.x;
  int dir = wg >> 6;
  int j0 = (wg & 63) * 16;
  int tid = threadIdx.x, lane = tid & 63, g = tid >> 6;
  int lm = lane & 15, lk = (lane >> 4) * 8, lr = lane >> 4;
  int s = dir ? (S_LEN - 1 - t) : t;
  const short* WhT = dir ? WhT_b : WhT_f;
  const short* hin = dir ? hin_b : hin_f;
  short* hout = dir ? hout_b : hout_f;
  float* cbuf = dir ? c_b : c_f;
  int ncol = g * HID + j0 + lm;

  floatx4 acc[4];
  for (int mt = 0; mt < 4; mt++)
    for (int r = 0; r < 4; r++) acc[mt][r] = 0.f;

  {
    const short* Wrow = WhT + (size_t)ncol * HID;
#pragma unroll 4
    for (int kt = 0; kt < HID; kt += 32) {
      short8 bfrag = *(const short8*)&Wrow[kt + lk];
#pragma unroll
      for (int mt = 0; mt < 4; mt++) {
        short8 afrag = *(const short8*)&hin[(mt * 16 + lm) * HID + kt + lk];
        acc[mt] = __builtin_amdgcn_mfma_f32_16x16x32_bf16(afrag, bfrag, acc[mt], 0, 0, 0);
      }
    }
  }
  if (fused) {
    const short* Wrow = (dir ? WxT_b : WxT_f) + (size_t)ncol * HID;
    const short* Xb = X + (size_t)s * BATCH * EMB;
#pragma unroll 4
    for (int kt = 0; kt < EMB; kt += 32) {
      short8 bfrag = *(const short8*)&Wrow[kt + lk];
#pragma unroll
      for (int mt = 0; mt < 4; mt++) {
        short8 afrag = *(const short8*)&Xb[(mt * 16 + lm) * EMB + kt + lk];
        acc[mt] = __builtin_amdgcn_mfma_f32_16x16x32_bf16(afrag, bfrag, acc[mt], 0, 0, 0);
      }
    }
  }

  __shared__ float gl[4][64][16];
  const short* Gin = dir ? Gin_b : Gin_f;
  const float* bias = dir ? bias_b : bias_f;
#pragma unroll
  for (int mt = 0; mt < 4; mt++)
    for (int r = 0; r < 4; r++) {
      int m = mt * 16 + lr * 4 + r;
      float v = acc[mt][r];
      if (fused) v += bias[ncol];
      else       v += bf2f(Gin[(size_t)(s * BATCH + m) * GATES + ncol]);
      gl[g][m][lm] = v;
    }
  __syncthreads();

  for (int p = tid; p < BATCH * 16; p += 256) {
    int m = p >> 4, nl = p & 15;
    int hcol = j0 + nl;
    float iv = gl[0][m][nl], fv = gl[1][m][nl], gv = gl[2][m][nl], ov = gl[3][m][nl];
    float co = cbuf[m * HID + hcol];
    float si = 1.f / (1.f + __expf(-iv));
    float sf = 1.f / (1.f + __expf(-fv));
    float so = 1.f / (1.f + __expf(-ov));
    float cn = sf * co + si * tanhf(gv);
    float hn = so * tanhf(cn);
    cbuf[m * HID + hcol] = cn;
    hout[m * HID + hcol] = f2bf(hn);
    out[(size_t)m * (S_LEN * 2 * HID) + (size_t)s * (2 * HID) + dir * HID + hcol] = hn;
    if (t == S_LEN - 1) {
      size_t hid_base = (size_t)BATCH * S_LEN * 2 * HID;
      out[hid_base + (size_t)m * (2 * HID) + dir * HID + hcol] = hn;
      out[hid_base + (size_t)BATCH * 2 * HID + (size_t)m * (2 * HID) + dir * HID + hcol] = cn;
    }
  }
}

// ---------------- persistent recurrence: all 512 steps in ONE cooperative kernel.
// 256 WGs (1/CU): WG wg -> dir = wg>>7, h-cols j0..j0+7 (32 gate-cols).
// Wh slice lives in LDS (66 KB; immune to the barrier's cache invalidations,
// zero VGPR cost). h loads are batch-issued into registers before the MFMA
// chain. Barrier = round-2's proven acquire/release tree (per direction).
__global__ __launch_bounds__(256, 1) void k_recur(
    const short* __restrict__ Gin_f, const short* __restrict__ Gin_b,
    const short* __restrict__ WhT_f, const short* __restrict__ WhT_b,
    short* __restrict__ hf1, short* __restrict__ hf2,
    short* __restrict__ hb1, short* __restrict__ hb2,
    unsigned* __restrict__ bar,
    float* __restrict__ out) {
  int wg = blockIdx.x;
  int dir = wg >> 7;
  int l = wg & 127;
  int grp = l >> 4;  // 8 groups of 16 per direction
  int j0 = l * 8;
  int tid = threadIdx.x;
  int w = tid >> 6;
  int lane = tid & 63;
  int lm = lane & 15, lr = lane >> 4;
  int lk = lr * 8;
  const short* WhT = dir ? WhT_b : WhT_f;
  const short* Gin = dir ? Gin_b : Gin_f;
  short* hin  = dir ? hb1 : hf1;
  short* hout = dir ? hb2 : hf2;

  unsigned* l1c = bar + (dir * 8 + grp) * 32;  // 128B-spaced counters
  unsigned* rtc = bar + (16 + dir) * 32;
  unsigned* rel = bar + (18 + dir) * 32;

  // gate-column of this lane's B fragment: acc0 -> gc0 (gates 0/1), acc1 -> gc1 (gates 2/3)
  int gc0 = ((lm >> 3) << 10) + j0 + (lm & 7);
  int gc1 = gc0 + 2048;
  int rowbase = w * 16 + lr * 4;

  // ---- stage this WG's Wh slice into LDS once: layout [col32][1024+8] shorts.
  // col32 = gate_pair*16 + lm; stride 1032 shorts (2064 B) -> within each
  // 16-lane quarter the 16 lanes spread 2-way over banks (the b128 floor).
  __shared__ __align__(16) short wlds[32 * 1032];
  for (int idx = tid; idx < 4096; idx += 256) {
    int col = idx >> 7, kc = idx & 127;
    int gcol = (col >> 3) * 1024 + j0 + (col & 7);
    *(short8*)&wlds[col * 1032 + kc * 8] = *(const short8*)&WhT[(size_t)gcol * HID + kc * 8];
  }
  __syncthreads();
  const short* w0p = &wlds[lm * 1032 + lk];         // col32 = lm      (gates 0/1)
  const short* w1p = &wlds[(16 + lm) * 1032 + lk];  // col32 = 16+lm   (gates 2/3)

  float c0 = 0.f, c1 = 0.f;        // persistent cell state (2 rows per lane)
  int rbase = (lm < 8) ? 0 : 2;    // r-split: low lanes rows r=0,1; high lanes r=2,3
  int hcol = j0 + (lm & 7);

  // prefetch Gin for step 0 (register-resident across the barrier)
  short gv0[4], gv1[4];
  {
    int s0 = dir ? (S_LEN - 1) : 0;
    const short* gin = Gin + (size_t)s0 * BATCH * GATES;
#pragma unroll
    for (int r = 0; r < 4; r++) {
      gv0[r] = gin[(size_t)(rowbase + r) * GATES + gc0];
      gv1[r] = gin[(size_t)(rowbase + r) * GATES + gc1];
    }
  }

  for (int t = 0; t < S_LEN; t++) {
    int s = dir ? (S_LEN - 1 - t) : t;

    // 1) batch-issue all 32 h fragment loads (fresh after the acquire barrier)
    const short* hrow = hin + (size_t)(w * 16 + lm) * HID;
    short8 ha[32];
#pragma unroll
    for (int kt = 0; kt < 32; kt++) ha[kt] = *(const short8*)&hrow[kt * 32 + lk];

    // 2) MFMA chain: LDS weight fragments x register h fragments
    floatx4 acc0 = {0.f, 0.f, 0.f, 0.f};
    floatx4 acc1 = {0.f, 0.f, 0.f, 0.f};
#pragma unroll
    for (int kt = 0; kt < 32; kt++) {
      short8 b0 = *(const short8*)&w0p[kt * 32];
      short8 b1 = *(const short8*)&w1p[kt * 32];
      acc0 = __builtin_amdgcn_mfma_f32_16x16x32_bf16(ha[kt], b0, acc0, 0, 0, 0);
      acc1 = __builtin_amdgcn_mfma_f32_16x16x32_bf16(ha[kt], b1, acc1, 0, 0, 0);
    }
#pragma unroll
    for (int r = 0; r < 4; r++) {
      acc0[r] += bf2f(gv0[r]);
      acc1[r] += bf2f(gv1[r]);
    }

    // 3) prefetch next step's Gin (overlaps pointwise + barrier)
    if (t + 1 < S_LEN) {
      int sn = dir ? (S_LEN - 2 - t) : (t + 1);
      const short* gin = Gin + (size_t)sn * BATCH * GATES;
#pragma unroll
      for (int r = 0; r < 4; r++) {
        gv0[r] = gin[(size_t)(rowbase + r) * GATES + gc0];
        gv1[r] = gin[(size_t)(rowbase + r) * GATES + gc1];
      }
    }

    // 4) gate exchange + pointwise update
    float sw0[4], sw1[4];
#pragma unroll
    for (int r = 0; r < 4; r++) {
      sw0[r] = __shfl_xor(acc0[r], 8, 64);
      sw1[r] = __shfl_xor(acc1[r], 8, 64);
    }

#pragma unroll
    for (int rr = 0; rr < 2; rr++) {
      int r = rbase + rr;
      float iv = (lm < 8) ? acc0[r] : sw0[r];
      float fv = (lm < 8) ? sw0[r] : acc0[r];
      float gg = (lm < 8) ? acc1[r] : sw1[r];
      float ov = (lm < 8) ? sw1[r] : acc1[r];
      float cprev = rr ? c1 : c0;
      float si = 1.f / (1.f + __expf(-iv));
      float sf = 1.f / (1.f + __expf(-fv));
      float so = 1.f / (1.f + __expf(-ov));
      float cn = sf * cprev + si * tanhf(gg);
      float hn = so * tanhf(cn);
      if (rr) c1 = cn; else c0 = cn;
      int row = rowbase + r;
      hout[row * HID + hcol] = f2bf(hn);
      out[(size_t)row * (S_LEN * 2 * HID) + (size_t)s * (2 * HID) + dir * HID + hcol] = hn;
      if (t == S_LEN - 1) {
        size_t hid_base = (size_t)BATCH * S_LEN * 2 * HID;
        out[hid_base + (size_t)row * (2 * HID) + dir * HID + hcol] = hn;
        out[hid_base + (size_t)BATCH * 2 * HID + (size_t)row * (2 * HID) + dir * HID + hcol] = cn;
      }
    }

    // 5) barrier (round-2 proven): syncthreads drains stores, leader fences
    //    (release: wbl2), arrive tree with acq_rel atomics, spin on acquire.
    if (t + 1 < S_LEN) {
      __syncthreads();  // all WG stores drained (vmcnt 0)
      if (tid == 0) {
        __threadfence();  // agent-scope release: WG's h stores device-visible
        unsigned prev = __hip_atomic_fetch_add(l1c, 1u, __ATOMIC_ACQ_REL, __HIP_MEMORY_SCOPE_AGENT);
        if ((prev & 15u) == 15u) {  // last of 16 in group for this epoch
          unsigned p2 = __hip_atomic_fetch_add(rtc, 1u, __ATOMIC_ACQ_REL, __HIP_MEMORY_SCOPE_AGENT);
          if ((p2 & 7u) == 7u)      // last of 8 groups
            __hip_atomic_store(rel, (unsigned)(t + 1), __ATOMIC_RELEASE, __HIP_MEMORY_SCOPE_AGENT);
        }
        while (__hip_atomic_load(rel, __ATOMIC_ACQUIRE, __HIP_MEMORY_SCOPE_AGENT) < (unsigned)(t + 1)) {
          __builtin_amdgcn_s_sleep(1);
        }
      }
      __syncthreads();
    }
    short* tmp = hin; hin = hout; hout = tmp;
  }
}

extern "C" void kernel_launch(void* const* d_in, const int* in_sizes, int n_in,
                              void* d_out, int out_size, void* d_ws, size_t ws_size,
                              hipStream_t stream) {
  const int*   tok   = (const int*)d_in[0];
  const float* table = (const float*)d_in[1];
  const float* Wx_f  = (const float*)d_in[2];
  const float* Wh_f  = (const float*)d_in[3];
  const float* b_f   = (const float*)d_in[4];
  const float* Wx_b  = (const float*)d_in[5];
  const float* Wh_b  = (const float*)d_in[6];
  const float* b_b   = (const float*)d_in[7];
  float* out = (float*)d_out;

  char* w = (char*)d_ws;
  short* WxTf = (short*)(w + 0);          // 8 MB each
  short* WxTb = (short*)(w + 8388608);
  short* WhTf = (short*)(w + 16777216);
  short* WhTb = (short*)(w + 25165824);
  char* state = w + 33554432;             // 1 MB state block
  short* h_f1 = (short*)(state);
  short* h_b1 = (short*)(state + 131072);
  float* c_f  = (float*)(state + 262144);   // fallback-only; doubles as barrier area
  float* c_b  = (float*)(state + 524288);
  short* h_f2 = (short*)(state + 786432);
  short* h_b2 = (short*)(state + 917504);
  unsigned* bar = (unsigned*)(state + 262144);  // reuses c_f area (zeroed by k_zero)
  short* X    = (short*)(w + 34603008);   // 64 MB
  short* Ginf = (short*)(w + 101711872);  // 256 MB
  short* Ginb = (short*)(w + 370147328);  // 256 MB
  int fused = (ws_size < 638582784ull) ? 1 : 0;

  k_gather<<<dim3(M_ROWS), dim3(256), 0, stream>>>(tok, table, X);
  k_transpose<<<dim3(32, 128), dim3(256), 0, stream>>>(Wx_f, WxTf);
  k_transpose<<<dim3(32, 128), dim3(256), 0, stream>>>(Wx_b, WxTb);
  k_transpose<<<dim3(32, 128), dim3(256), 0, stream>>>(Wh_f, WhTf);
  k_transpose<<<dim3(32, 128), dim3(256), 0, stream>>>(Wh_b, WhTb);
  k_zero<<<dim3(768), dim3(256), 0, stream>>>((uint32_t*)state, 786432 / 4);

  int use_persistent = 0;
  if (!fused) {
    k_gemm_in<<<dim3(32, 256, 2), dim3(256), 0, stream>>>(X, WxTf, WxTb, b_f, b_b, Ginf, Ginb);
    void* args[10];
    args[0] = (void*)&Ginf;  args[1] = (void*)&Ginb;
    args[2] = (void*)&WhTf;  args[3] = (void*)&WhTb;
    args[4] = (void*)&h_f1;  args[5] = (void*)&h_f2;
    args[6] = (void*)&h_b1;  args[7] = (void*)&h_b2;
    args[8] = (void*)&bar;   args[9] = (void*)&out;
    hipError_t err = hipLaunchCooperativeKernel((const void*)k_recur, dim3(256), dim3(256),
                                                args, 0, stream);
    if (err == hipSuccess) use_persistent = 1;
    else (void)hipGetLastError();  // clear sticky error, fall back to per-step loop
  }

  if (!use_persistent) {
    for (int t = 0; t < S_LEN; t++) {
      const short* hinf = (t & 1) ? h_f2 : h_f1;
      const short* hinb = (t & 1) ? h_b2 : h_b1;
      short* houtf = (t & 1) ? h_f1 : h_f2;
      short* houtb = (t & 1) ? h_b1 : h_b2;
      k_step<<<dim3(128), dim3(256), 0, stream>>>(t, fused, Ginf, Ginb, X, WxTf, WxTb, b_f, b_b,
                                                  WhTf, WhTb, hinf, hinb, houtf, houtb, c_f, c_b, out);
    }
  }
}